// Round 5
// baseline (451.725 us; speedup 1.0000x reference)
//
#include <hip/hip_runtime.h>
#include <math.h>

// Problem constants (B=2, T=2048, E=1024, H=16, S=64)
#define T_SEQ 2048
#define E_DIM 1024
#define NH    16
#define HS    64
#define NB    2
#define M_ROWS 4096

typedef __attribute__((ext_vector_type(8))) short bf16x8;
typedef __attribute__((ext_vector_type(4))) short bf16x4;
typedef __attribute__((ext_vector_type(4))) float f32x4;

#define AS1 __attribute__((address_space(1)))
#define AS3 __attribute__((address_space(3)))

#define LOG2E 1.4426950408889634f

// 16x16x16 bf16 MFMA (K=16): B-operand k-index (quad*4+j) matches the
// C-layout row index (quad*4+r) — QK^T's S^T accumulator feeds PV directly.
__device__ __forceinline__ f32x4 mfma16(bf16x4 a, bf16x4 b, f32x4 c) {
    return __builtin_amdgcn_mfma_f32_16x16x16bf16_1k(a, b, c, 0, 0, 0);
}

__device__ __forceinline__ ushort f2bf(float f) {
    union { float f; unsigned u; } c; c.f = f;
    unsigned r = c.u + 0x7fffu + ((c.u >> 16) & 1u);
    return (ushort)(r >> 16);
}
__device__ __forceinline__ ushort f2bf_trunc(float f) {
    union { float f; unsigned u; } c; c.f = f;
    return (ushort)(c.u >> 16);
}

__device__ __forceinline__ void load_lds16(const ushort* g, ushort* l) {
    // 16B per lane, LDS dest = wave-uniform base + lane*16 (HW behavior)
    __builtin_amdgcn_global_load_lds((const AS1 unsigned int*)g,
                                     (AS3 unsigned int*)l, 16, 0, 0);
}

// ---------------------------------------------------------------------------
// fp32 -> bf16 conversion for x and the four weight matrices.
// Block 0 additionally zeroes the per-slot merge counters for flash_attn6.
// ---------------------------------------------------------------------------
__global__ __launch_bounds__(256) void cvt_all(
    const float* __restrict__ x,  const float* __restrict__ Wk,
    const float* __restrict__ Wq, const float* __restrict__ Wv,
    const float* __restrict__ Wu,
    ushort* __restrict__ xb,  ushort* __restrict__ Wkb,
    ushort* __restrict__ Wqb, ushort* __restrict__ Wvb,
    ushort* __restrict__ Wub, int* __restrict__ Cnt)
{
    if (blockIdx.x == 0) {
#pragma unroll
        for (int i = 0; i < 4; ++i) Cnt[threadIdx.x * 4 + i] = 0;
    }
    int i4 = blockIdx.x * 256 + threadIdx.x;   // 0 .. 2M-1 (float4 units)
    int region = i4 >> 18;
    const float* src; ushort* dst; int off;
    if      (region < 4)  { src = x;  dst = xb;  off = i4; }
    else if (region == 4) { src = Wk; dst = Wkb; off = i4 - (4 << 18); }
    else if (region == 5) { src = Wq; dst = Wqb; off = i4 - (5 << 18); }
    else if (region == 6) { src = Wv; dst = Wvb; off = i4 - (6 << 18); }
    else                  { src = Wu; dst = Wub; off = i4 - (7 << 18); }
    float4 v = *(const float4*)(src + (size_t)off * 4);
    ushort4 o; o.x = f2bf(v.x); o.y = f2bf(v.y); o.z = f2bf(v.z); o.w = f2bf(v.w);
    *(ushort4*)(dst + (size_t)off * 4) = o;
}

// ---------------------------------------------------------------------------
// bf16 MFMA GEMM core with DOUBLE-BUFFERED staging and ONE barrier per
// K-iteration. 128x128 tile, BK=32, 4 waves in 2x2, 16 MFMA/wave/iter.
// 32 KB LDS -> multi-block/CU: inter-block overlap hides the per-tile vmcnt
// drain (measured: ties every fancier 2-phase structure at this shape).
// ---------------------------------------------------------------------------
__device__ __forceinline__ void gemm_core_db(
    const ushort* __restrict__ A, const ushort* __restrict__ W,
    int m0, int n0, ushort* As, ushort* Bs, f32x4 acc[4][4])
{
    const int tid  = threadIdx.x;
    const int lane = tid & 63, w = tid >> 6;
    const int quad = lane >> 4, l16 = lane & 15;
    const int wm = w & 1, wn = w >> 1;

    const int rl   = lane >> 2;                       // row-in-chunk 0..15
    const int gsw  = (lane & 3) ^ ((lane >> 3) & 3);  // swizzled global chunk
    const int fsw  = (l16 >> 1) & 3;                  // frag-read xor factor

    const f32x4 zero = {0.f, 0.f, 0.f, 0.f};
#pragma unroll
    for (int mt = 0; mt < 4; ++mt)
#pragma unroll
        for (int nt = 0; nt < 4; ++nt) acc[mt][nt] = zero;

    // initial stage into buffer 0
#pragma unroll
    for (int i = 0; i < 2; ++i) {
        int c = i * 4 + w;                 // chunk 0..7 (16 rows x 64B)
        int row = c * 16 + rl;
        load_lds16(A + (size_t)(m0 + row) * E_DIM + gsw * 8, As + c * 512);
        load_lds16(W + (size_t)(n0 + row) * E_DIM + gsw * 8, Bs + c * 512);
    }

    for (int k0 = 0; k0 < E_DIM; k0 += 32) {
        const int buf = (k0 >> 5) & 1;
        ushort* Ab = As + buf * 4096;
        ushort* Bb = Bs + buf * 4096;
        __syncthreads();   // own-wave vmcnt drained -> buf ready; syncs reuse
        if (k0 + 32 < E_DIM) {
            ushort* An = As + (buf ^ 1) * 4096;
            ushort* Bn = Bs + (buf ^ 1) * 4096;
#pragma unroll
            for (int i = 0; i < 2; ++i) {
                int c = i * 4 + w;
                int row = c * 16 + rl;
                load_lds16(A + (size_t)(m0 + row) * E_DIM + k0 + 32 + gsw * 8,
                           An + c * 512);
                load_lds16(W + (size_t)(n0 + row) * E_DIM + k0 + 32 + gsw * 8,
                           Bn + c * 512);
            }
        }
        bf16x8 af[4], bfr[4];
#pragma unroll
        for (int mt = 0; mt < 4; ++mt)
            af[mt] = *(const bf16x8*)(Ab + (wm * 64 + mt * 16 + l16) * 32
                                      + ((quad ^ fsw) * 8));
#pragma unroll
        for (int nt = 0; nt < 4; ++nt)
            bfr[nt] = *(const bf16x8*)(Bb + (wn * 64 + nt * 16 + l16) * 32
                                       + ((quad ^ fsw) * 8));
#pragma unroll
        for (int mt = 0; mt < 4; ++mt)
#pragma unroll
            for (int nt = 0; nt < 4; ++nt)
                acc[mt][nt] = __builtin_amdgcn_mfma_f32_16x16x32_bf16(
                    af[mt], bfr[nt], acc[mt][nt], 0, 0, 0);
    }
}

// ---------------------------------------------------------------------------
// QKV GEMM (z-grid) with fused epilogues:
//  z=0: K -> LN(kln) -> Kb
//  z=1: Q -> LN(qln) * 0.125*log2e -> Qb
//  z=2: V -> transposed store -> Vt [bh][d][t]
// ---------------------------------------------------------------------------
__global__ __launch_bounds__(256) void gemm_qkv(
    const ushort* __restrict__ A,
    const ushort* __restrict__ W0, const ushort* __restrict__ W1,
    const ushort* __restrict__ W2,
    ushort* __restrict__ Kb, ushort* __restrict__ Qb, ushort* __restrict__ Vt,
    const float* __restrict__ kw, const float* __restrict__ kbias,
    const float* __restrict__ qw, const float* __restrict__ qbias)
{
    __shared__ ushort As[2 * 128 * 32];   // 16 KB
    __shared__ ushort Bs[2 * 128 * 32];   // 16 KB
    const int z = blockIdx.z;
    const ushort* W = (z == 0) ? W0 : (z == 1) ? W1 : W2;
    const int m0 = blockIdx.y * 128, n0 = blockIdx.x * 128;
    f32x4 acc[4][4];
    gemm_core_db(A, W, m0, n0, As, Bs, acc);

    const int lane = threadIdx.x & 63, w = threadIdx.x >> 6;
    const int quad = lane >> 4, l16 = lane & 15;
    const int wm = w & 1, wn = w >> 1;
    const int row0 = m0 + wm * 64;
    const int col0 = n0 + wn * 64;

    if (z < 2) {
        ushort* C = z ? Qb : Kb;
        const float* lw = z ? qw : kw;
        const float* lb = z ? qbias : kbias;
        const float scale = z ? (0.125f * LOG2E) : 1.0f;
        float wv[4], bv_[4];
#pragma unroll
        for (int nt = 0; nt < 4; ++nt) {
            wv[nt]  = lw[nt * 16 + l16];
            bv_[nt] = lb[nt * 16 + l16];
        }
#pragma unroll
        for (int mt = 0; mt < 4; ++mt)
#pragma unroll
            for (int r = 0; r < 4; ++r) {
                float v[4], d[4];
#pragma unroll
                for (int nt = 0; nt < 4; ++nt) v[nt] = acc[mt][nt][r];
                float s = v[0] + v[1] + v[2] + v[3];
                s += __shfl_xor(s, 1); s += __shfl_xor(s, 2);
                s += __shfl_xor(s, 4); s += __shfl_xor(s, 8);
                float mu = s * (1.0f / 64.0f);
                float q2 = 0.f;
#pragma unroll
                for (int nt = 0; nt < 4; ++nt) { d[nt] = v[nt] - mu; q2 += d[nt] * d[nt]; }
                q2 += __shfl_xor(q2, 1); q2 += __shfl_xor(q2, 2);
                q2 += __shfl_xor(q2, 4); q2 += __shfl_xor(q2, 8);
                float rin = rsqrtf(q2 * (1.0f / 64.0f) + 1e-5f);
                int row = row0 + mt * 16 + quad * 4 + r;
#pragma unroll
                for (int nt = 0; nt < 4; ++nt)
                    C[(size_t)row * E_DIM + col0 + nt * 16 + l16] =
                        f2bf((d[nt] * rin * wv[nt] + bv_[nt]) * scale);
            }
    } else {
        // V: transposed store Vt[(b*NH+h)*64 + d][t]
        const int bidx = m0 >> 11;
        const int hh   = col0 >> 6;
        const int t0   = (m0 & 2047) + wm * 64;
#pragma unroll
        for (int mt = 0; mt < 4; ++mt)
#pragma unroll
            for (int nt = 0; nt < 4; ++nt) {
                ushort4 pk = make_ushort4(f2bf(acc[mt][nt][0]), f2bf(acc[mt][nt][1]),
                                          f2bf(acc[mt][nt][2]), f2bf(acc[mt][nt][3]));
                size_t off = ((size_t)(bidx * NH + hh) * 64 + nt * 16 + l16) * T_SEQ
                             + t0 + mt * 16 + quad * 4;
                *(ushort4*)(Vt + off) = pk;
            }
    }
}

// ---------------------------------------------------------------------------
// Output GEMM: 128x128 tiles (grid 8x32 = 256 blocks), dbuf core, fp32 store.
// ---------------------------------------------------------------------------
__global__ __launch_bounds__(256) void gemm_o(
    const ushort* __restrict__ A, const ushort* __restrict__ W,
    float* __restrict__ C)
{
    __shared__ ushort As[2 * 128 * 32];
    __shared__ ushort Bs[2 * 128 * 32];
    const int m0 = blockIdx.y * 128, n0 = blockIdx.x * 128;
    f32x4 acc[4][4];
    gemm_core_db(A, W, m0, n0, As, Bs, acc);

    const int lane = threadIdx.x & 63, w = threadIdx.x >> 6;
    const int quad = lane >> 4, l16 = lane & 15;
    const int row0 = m0 + (w & 1) * 64;
    const int col0 = n0 + (w >> 1) * 64;
#pragma unroll
    for (int mt = 0; mt < 4; ++mt)
#pragma unroll
        for (int nt = 0; nt < 4; ++nt)
#pragma unroll
            for (int r = 0; r < 4; ++r)
                C[(size_t)(row0 + mt * 16 + quad * 4 + r) * E_DIM
                  + col0 + nt * 16 + l16] = acc[mt][nt][r];
}

// ---------------------------------------------------------------------------
// Flash attention v7: SPLIT-K causal flash with FUSED merge. Fixed-max exp2
// softmax => partials exactly additive. Each half writes raw f32 partials;
// the LAST half to finish a slot (device-scope atomic counter, Guideline-16
// fence protocol) keeps its own half in registers, reads only the partner's
// partials, normalizes, and stores Ob directly. qt=0 stores directly (no
// partner). Grid 2048 LPT-ordered; (256,5) -> 5 blocks/CU (LDS 5x32KB).
// ---------------------------------------------------------------------------
__global__ __launch_bounds__(256, 5) void flash_attn7(
    const ushort* __restrict__ Qg, const ushort* __restrict__ Kg,
    const ushort* __restrict__ Vt, float* __restrict__ Pbuf,
    float* __restrict__ Lbuf, ushort* __restrict__ O, int* __restrict__ Cnt)
{
    __shared__ ushort Ks[2][64 * 64];   // 16 KB
    __shared__ ushort Vs[2][64 * 64];   // 16 KB

    const int tid  = threadIdx.x;
    const int lane = tid & 63, w = tid >> 6;
    const int quad = lane >> 4, l16 = lane & 15;

    const int pair  = blockIdx.x >> 1;          // 0..1023
    const int split = blockIdx.x & 1;
    const int bh = pair & 31;
    const int qt = 31 - (pair >> 5);            // longest work first (LPT)
    const int b = bh >> 4, h = bh & 15;

    const int ntile = qt + 1;
    const int hmid  = ntile >> 1;               // split0: [0,hmid) split1: [hmid,ntile)
    const int jt0 = split ? hmid  : 0;
    const int jt1 = split ? ntile : hmid;
    if (jt0 >= jt1) return;                     // qt=0 split0: empty (uniform)

    const int slot = (bh << 5) | qt;

    const ushort* Qbase = Qg + ((size_t)b * T_SEQ) * E_DIM + h * HS;
    const ushort* Kbase = Kg + ((size_t)b * T_SEQ) * E_DIM + h * HS;
    const ushort* Vbase = Vt + ((size_t)bh * HS) * T_SEQ;   // [d][t]

    const int rloc = lane >> 3;
    const int gswc = (lane & 7) ^ rloc;     // swizzled global chunk (staging)
    const int sw   = l16 & 7;               // frag-read xor factor

    // Q B-frags (16x16x32): B[n=q][k=d], lane n=l16 -> q row, k=quad*8+j
    bf16x8 aq[2];
#pragma unroll
    for (int ks = 0; ks < 2; ++ks)
        aq[ks] = *(const bf16x8*)(Qbase + (size_t)(qt * 64 + w * 16 + l16) * E_DIM
                                  + ks * 32 + quad * 8);

    const f32x4 zero = {0.f, 0.f, 0.f, 0.f};
    f32x4 o_acc[4];                     // O^T: lane col=q(l16), rows d=quad*4+r
#pragma unroll
    for (int dt = 0; dt < 4; ++dt) o_acc[dt] = zero;
    float l_acc = 0.f;                  // q is lane-fixed -> scalar l

    // initial stage of tile jt0 into buffer 0
#pragma unroll
    for (int i = 0; i < 2; ++i) {
        int cc = w * 2 + i, row = cc * 8 + rloc;
        load_lds16(Kbase + (size_t)(jt0 * 64 + row) * E_DIM + gswc * 8,
                   Ks[0] + cc * 512);
        load_lds16(Vbase + (size_t)row * T_SEQ + jt0 * 64 + gswc * 8,
                   Vs[0] + cc * 512);
    }

    const float M8 = 8.0f * LOG2E;   // fixed max in exp2 domain

    for (int jt = jt0; jt < jt1; ++jt) {
        const int buf = (jt - jt0) & 1;
        __syncthreads();   // drains vmcnt -> buf ready; syncs buffer reuse
        if (jt + 1 < jt1) {
#pragma unroll
            for (int i = 0; i < 2; ++i) {
                int cc = w * 2 + i, row = cc * 8 + rloc;
                load_lds16(Kbase + (size_t)(jt + 1) * 64 * E_DIM
                           + (size_t)row * E_DIM + gswc * 8, Ks[buf ^ 1] + cc * 512);
                load_lds16(Vbase + (size_t)row * T_SEQ + (jt + 1) * 64 + gswc * 8,
                           Vs[buf ^ 1] + cc * 512);
            }
        }

        // S^T = K Q^T: tiles over t (nt). A=K-frag (m=t), B=aq (n=q).
        f32x4 sa[4];
#pragma unroll
        for (int nt = 0; nt < 4; ++nt) sa[nt] = zero;
        __builtin_amdgcn_s_setprio(1);
#pragma unroll
        for (int ks = 0; ks < 2; ++ks) {
            int cp = ((ks * 4 + quad) ^ sw) * 8;
#pragma unroll
            for (int nt = 0; nt < 4; ++nt) {
                bf16x8 bk = *(const bf16x8*)(Ks[buf] + (nt * 16 + l16) * 64 + cp);
                sa[nt] = __builtin_amdgcn_mfma_f32_16x16x32_bf16(bk, aq[ks], sa[nt], 0, 0, 0);
            }
        }
        __builtin_amdgcn_s_setprio(0);

        if (jt == qt) {   // causal mask: t > q (only split1's last tile)
#pragma unroll
            for (int nt = 0; nt < 4; ++nt)
#pragma unroll
                for (int r = 0; r < 4; ++r)
                    if (nt * 16 + quad * 4 + r > w * 16 + l16) sa[nt][r] = -1e30f;
        }

        // p = exp2(s - 8*log2e); pairwise l accumulation (short dep chains)
        bf16x4 bp[4];
        float lp[4];
#pragma unroll
        for (int nt = 0; nt < 4; ++nt) {
            float p0 = __builtin_amdgcn_exp2f(sa[nt][0] - M8);
            float p1 = __builtin_amdgcn_exp2f(sa[nt][1] - M8);
            float p2 = __builtin_amdgcn_exp2f(sa[nt][2] - M8);
            float p3 = __builtin_amdgcn_exp2f(sa[nt][3] - M8);
            bp[nt][0] = (short)f2bf_trunc(p0);
            bp[nt][1] = (short)f2bf_trunc(p1);
            bp[nt][2] = (short)f2bf_trunc(p2);
            bp[nt][3] = (short)f2bf_trunc(p3);
            lp[nt] = (p0 + p1) + (p2 + p3);
        }
        l_acc += (lp[0] + lp[1]) + (lp[2] + lp[3]);

        // O^T += V^T @ P^T : A = V^T rows d (from Vs), B = bp[kt] (k = t)
        __builtin_amdgcn_s_setprio(1);
#pragma unroll
        for (int kt = 0; kt < 4; ++kt) {
            const int tt = kt * 16 + quad * 4;          // t of this k-slice
            const int ch = tt >> 3, el = tt & 7;
#pragma unroll
            for (int dt = 0; dt < 4; ++dt) {
                const int vd = dt * 16 + l16;
                bf16x4 va = *(const bf16x4*)(Vs[buf] + vd * 64
                                             + ((ch ^ (vd & 7)) << 3) + el);
                o_acc[dt] = mfma16(va, bp[kt], o_acc[dt]);
            }
        }
        __builtin_amdgcn_s_setprio(0);
    }

    // ---- epilogue ----------------------------------------------------------
    l_acc += __shfl_xor(l_acc, 16);
    l_acc += __shfl_xor(l_acc, 32);
    const int q = w * 16 + l16;
    const int trow = qt * 64 + q;

    if (hmid == 0) {
        // qt == 0 (only split1 runs): no partner -> direct normalized store.
        const float inv = 1.0f / l_acc;
#pragma unroll
        for (int dt = 0; dt < 4; ++dt) {
            ushort4 pk = make_ushort4(f2bf(o_acc[dt][0] * inv), f2bf(o_acc[dt][1] * inv),
                                      f2bf(o_acc[dt][2] * inv), f2bf(o_acc[dt][3] * inv));
            *(ushort4*)(O + ((size_t)b * T_SEQ + trow) * E_DIM + h * HS
                        + dt * 16 + quad * 4) = pk;
        }
        return;
    }

    // write RAW f32 partials (un-normalized) + partial l
    float* Po = Pbuf + (((size_t)split << 22) | ((size_t)slot << 12));
#pragma unroll
    for (int dt = 0; dt < 4; ++dt)
        *(f32x4*)(Po + q * 64 + dt * 16 + quad * 4) = o_acc[dt];
    if (quad == 0) Lbuf[(split << 16) | (slot << 6) | q] = l_acc;

    // last-done-half merges (device-scope fence + atomic, Guideline 16)
    __syncthreads();                     // all threads' stores drained (vmcnt0)
    volatile int* flag = (volatile int*)&Ks[0][0];   // LDS reuse, compute done
    if (tid == 0) {
        __threadfence();                 // release: block's stores -> device
        *flag = (atomicAdd(&Cnt[slot], 1) == 1);
    }
    __syncthreads();
    if (*flag) {
        __threadfence();                 // acquire: partner's stores visible
        const float* Pp = Pbuf + (((size_t)(split ^ 1) << 22) | ((size_t)slot << 12));
        const float lp = Lbuf[((split ^ 1) << 16) | (slot << 6) | q];
        const float inv = 1.0f / (l_acc + lp);
#pragma unroll
        for (int dt = 0; dt < 4; ++dt) {
            f32x4 pv = *(const f32x4*)(Pp + q * 64 + dt * 16 + quad * 4);
            ushort4 pk = make_ushort4(f2bf((o_acc[dt][0] + pv[0]) * inv),
                                      f2bf((o_acc[dt][1] + pv[1]) * inv),
                                      f2bf((o_acc[dt][2] + pv[2]) * inv),
                                      f2bf((o_acc[dt][3] + pv[3]) * inv));
            *(ushort4*)(O + ((size_t)b * T_SEQ + trow) * E_DIM + h * HS
                        + dt * 16 + quad * 4) = pk;
        }
    }
}

// ---------------------------------------------------------------------------
extern "C" void kernel_launch(void* const* d_in, const int* in_sizes, int n_in,
                              void* d_out, int out_size, void* d_ws, size_t ws_size,
                              hipStream_t stream) {
    const float* x     = (const float*)d_in[0];
    const float* Wk    = (const float*)d_in[1];
    const float* Wq    = (const float*)d_in[2];
    const float* Wv    = (const float*)d_in[3];
    const float* Wu    = (const float*)d_in[4];
    const float* kln_w = (const float*)d_in[5];
    const float* kln_b = (const float*)d_in[6];
    const float* qln_w = (const float*)d_in[7];
    const float* qln_b = (const float*)d_in[8];
    float* out = (float*)d_out;

    const size_t NE = (size_t)M_ROWS * E_DIM;   // 4M elems
    const size_t NW = (size_t)E_DIM * E_DIM;    // 1M elems
    ushort* xb  = (ushort*)d_ws;                // 4M
    ushort* Wkb = xb  + NE;                     // 1M each
    ushort* Wqb = Wkb + NW;
    ushort* Wvb = Wqb + NW;
    ushort* Wub = Wvb + NW;
    ushort* Kb  = Wub + NW;                     // 4M
    ushort* Qb  = Kb  + NE;                     // 4M
    ushort* Vt  = Qb  + NE;                     // 4M, [bh][d][t]
    ushort* Ob  = Vt  + NE;                     // 4M
    float*  Pbuf = (float*)(Ob + NE);           // 2 x 1024 x 4096 f32 = 32 MB
    float*  Lbuf = Pbuf + ((size_t)2 << 22);    // 2 x 65536 f32 = 512 KB
    int*    Cnt  = (int*)(Lbuf + 2 * 65536);    // 1024 ints

    // 1) fp32 -> bf16 (+ zero merge counters)
    cvt_all<<<8192, 256, 0, stream>>>(x, Wk, Wq, Wv, Wu, xb, Wkb, Wqb, Wvb, Wub, Cnt);

    // 2) K/Q/V projections (128x128 z-grid, dbuf) with fused LN + V-transpose
    gemm_qkv<<<dim3(E_DIM / 128, M_ROWS / 128, 3), 256, 0, stream>>>(
        xb, Wkb, Wqb, Wvb, Kb, Qb, Vt, kln_w, kln_b, qln_w, qln_b);

    // 3) Causal flash attention, split-K x2 (LPT) with FUSED merge
    flash_attn7<<<2048, 256, 0, stream>>>(Qb, Kb, Vt, Pbuf, Lbuf, Ob, Cnt);

    // 4) Output projection (128x128, dbuf) -> fp32 out
    gemm_o<<<dim3(E_DIM / 128, M_ROWS / 128), 256, 0, stream>>>(Ob, Wub, out);
}

// Round 6
// 185.381 us; speedup vs baseline: 2.4367x; 2.4367x over previous
//
#include <hip/hip_runtime.h>
#include <math.h>

// Problem constants (B=2, T=2048, E=1024, H=16, S=64)
#define T_SEQ 2048
#define E_DIM 1024
#define NH    16
#define HS    64
#define NB    2
#define M_ROWS 4096

typedef __attribute__((ext_vector_type(8))) short bf16x8;
typedef __attribute__((ext_vector_type(4))) short bf16x4;
typedef __attribute__((ext_vector_type(4))) float f32x4;

#define AS1 __attribute__((address_space(1)))
#define AS3 __attribute__((address_space(3)))

#define LOG2E 1.4426950408889634f

// 16x16x16 bf16 MFMA (K=16): B-operand k-index (quad*4+j) matches the
// C-layout row index (quad*4+r) — QK^T's S^T accumulator feeds PV directly.
__device__ __forceinline__ f32x4 mfma16(bf16x4 a, bf16x4 b, f32x4 c) {
    return __builtin_amdgcn_mfma_f32_16x16x16bf16_1k(a, b, c, 0, 0, 0);
}

__device__ __forceinline__ ushort f2bf(float f) {
    union { float f; unsigned u; } c; c.f = f;
    unsigned r = c.u + 0x7fffu + ((c.u >> 16) & 1u);
    return (ushort)(r >> 16);
}
__device__ __forceinline__ ushort f2bf_trunc(float f) {
    union { float f; unsigned u; } c; c.f = f;
    return (ushort)(c.u >> 16);
}

__device__ __forceinline__ void load_lds16(const ushort* g, ushort* l) {
    // 16B per lane, LDS dest = wave-uniform base + lane*16 (HW behavior)
    __builtin_amdgcn_global_load_lds((const AS1 unsigned int*)g,
                                     (AS3 unsigned int*)l, 16, 0, 0);
}

// ---------------------------------------------------------------------------
// fp32 -> bf16 conversion for x and the four weight matrices.
// Wk/Wq/Wv land contiguously -> packed Wqkv [3072][1024] for the fused GEMM.
// ---------------------------------------------------------------------------
__global__ __launch_bounds__(256) void cvt_all(
    const float* __restrict__ x,  const float* __restrict__ Wk,
    const float* __restrict__ Wq, const float* __restrict__ Wv,
    const float* __restrict__ Wu,
    ushort* __restrict__ xb,  ushort* __restrict__ Wkb,
    ushort* __restrict__ Wqb, ushort* __restrict__ Wvb,
    ushort* __restrict__ Wub)
{
    int i4 = blockIdx.x * 256 + threadIdx.x;   // 0 .. 2M-1 (float4 units)
    int region = i4 >> 18;
    const float* src; ushort* dst; int off;
    if      (region < 4)  { src = x;  dst = xb;  off = i4; }
    else if (region == 4) { src = Wk; dst = Wkb; off = i4 - (4 << 18); }
    else if (region == 5) { src = Wq; dst = Wqb; off = i4 - (5 << 18); }
    else if (region == 6) { src = Wv; dst = Wvb; off = i4 - (6 << 18); }
    else                  { src = Wu; dst = Wub; off = i4 - (7 << 18); }
    float4 v = *(const float4*)(src + (size_t)off * 4);
    ushort4 o; o.x = f2bf(v.x); o.y = f2bf(v.y); o.z = f2bf(v.z); o.w = f2bf(v.w);
    *(ushort4*)(dst + (size_t)off * 4) = o;
}

// ---------------------------------------------------------------------------
// bf16 MFMA GEMM core, 128x128 tile, BK=32, 4 waves, double-buffered (used by
// gemm_o). 32 KB LDS -> 3+ blocks/CU; inter-block overlap hides drains.
// ---------------------------------------------------------------------------
__device__ __forceinline__ void gemm_core_db(
    const ushort* __restrict__ A, const ushort* __restrict__ W,
    int m0, int n0, ushort* As, ushort* Bs, f32x4 acc[4][4])
{
    const int tid  = threadIdx.x;
    const int lane = tid & 63, w = tid >> 6;
    const int quad = lane >> 4, l16 = lane & 15;
    const int wm = w & 1, wn = w >> 1;

    const int rl   = lane >> 2;                       // row-in-chunk 0..15
    const int gsw  = (lane & 3) ^ ((lane >> 3) & 3);  // swizzled global chunk
    const int fsw  = (l16 >> 1) & 3;                  // frag-read xor factor

    const f32x4 zero = {0.f, 0.f, 0.f, 0.f};
#pragma unroll
    for (int mt = 0; mt < 4; ++mt)
#pragma unroll
        for (int nt = 0; nt < 4; ++nt) acc[mt][nt] = zero;

    // initial stage into buffer 0
#pragma unroll
    for (int i = 0; i < 2; ++i) {
        int c = i * 4 + w;                 // chunk 0..7 (16 rows x 64B)
        int row = c * 16 + rl;
        load_lds16(A + (size_t)(m0 + row) * E_DIM + gsw * 8, As + c * 512);
        load_lds16(W + (size_t)(n0 + row) * E_DIM + gsw * 8, Bs + c * 512);
    }

    for (int k0 = 0; k0 < E_DIM; k0 += 32) {
        const int buf = (k0 >> 5) & 1;
        ushort* Ab = As + buf * 4096;
        ushort* Bb = Bs + buf * 4096;
        __syncthreads();   // own-wave vmcnt drained -> buf ready; syncs reuse
        if (k0 + 32 < E_DIM) {
            ushort* An = As + (buf ^ 1) * 4096;
            ushort* Bn = Bs + (buf ^ 1) * 4096;
#pragma unroll
            for (int i = 0; i < 2; ++i) {
                int c = i * 4 + w;
                int row = c * 16 + rl;
                load_lds16(A + (size_t)(m0 + row) * E_DIM + k0 + 32 + gsw * 8,
                           An + c * 512);
                load_lds16(W + (size_t)(n0 + row) * E_DIM + k0 + 32 + gsw * 8,
                           Bn + c * 512);
            }
        }
        bf16x8 af[4], bfr[4];
#pragma unroll
        for (int mt = 0; mt < 4; ++mt)
            af[mt] = *(const bf16x8*)(Ab + (wm * 64 + mt * 16 + l16) * 32
                                      + ((quad ^ fsw) * 8));
#pragma unroll
        for (int nt = 0; nt < 4; ++nt)
            bfr[nt] = *(const bf16x8*)(Bb + (wn * 64 + nt * 16 + l16) * 32
                                       + ((quad ^ fsw) * 8));
#pragma unroll
        for (int mt = 0; mt < 4; ++mt)
#pragma unroll
            for (int nt = 0; nt < 4; ++nt)
                acc[mt][nt] = __builtin_amdgcn_mfma_f32_16x16x32_bf16(
                    af[mt], bfr[nt], acc[mt][nt], 0, 0, 0);
    }
}

// ---------------------------------------------------------------------------
// PHASE-INTERLEAVED QKV GEMM (T3+T4): 256x256 tile, 8 waves (2Mx4N), K-step
// 32, FOUR LDS buffers (4 x (A 16K + B 16K) = 128 KiB), prefetch distance 3.
// Per K-step, TWO phases, each: {ds_read frags, issue 2 gload_lds (stage step
// t+3), s_barrier, 16 MFMA (setprio)} ; ONE counted vmcnt per step (8 -> tail
// 4 -> 0), placed BEFORE the trailing barrier so the barrier publishes
// "panels t+1 retired" to all waves (vmcnt is per-wave; the barrier makes it
// cross-wave). Loads get ~6 phases (>600 cy) of MFMA cover; vmcnt never
// drains to 0 until the tail.
// Race-freedom: stage at step t targets buf (t+3)&3 = (t-1)&3; all waves'
// ds_reads of that buf completed before their step-(t-1) MFMAs (compiler
// lgkmcnt) which precede the trailing barrier the stager already passed.
// ---------------------------------------------------------------------------
__global__ __launch_bounds__(512, 2) void gemm_qkv_8p(
    const ushort* __restrict__ A, const ushort* __restrict__ Wqkv,
    ushort* __restrict__ Kb, ushort* __restrict__ Qb, ushort* __restrict__ Vt,
    const float* __restrict__ kw, const float* __restrict__ kbias,
    const float* __restrict__ qw, const float* __restrict__ qbias)
{
    extern __shared__ ushort smem[];           // 128 KiB
    ushort* SA = smem;                         // 4 x 8192 ushorts
    ushort* SB = smem + 4 * 8192;              // 4 x 8192 ushorts

    const int tid  = threadIdx.x;
    const int lane = tid & 63, w = tid >> 6;   // 8 waves
    const int quad = lane >> 4, l16 = lane & 15;
    const int wm = w & 1, wn = w >> 1;         // 2M x 4N wave grid

    const int lid = blockIdx.x;                // 0..191, bijective XCD swizzle
    const int swz = (lid & 7) * 24 + (lid >> 3);
    const int m0  = (swz & 15) * 256;
    const int n0  = (swz >> 4) * 256;          // packed N=3072

    const int rl  = lane >> 2;                 // row-in-chunk 0..15
    const int gsw = (lane & 3) ^ ((lane >> 3) & 3);  // swizzled src quarter
    const int cpq = ((quad ^ ((l16 >> 1) & 3)) * 8); // frag-read xor offset

    const ushort* Ag = A    + (size_t)(m0 + rl) * E_DIM + gsw * 8;
    const ushort* Bg = Wqkv + (size_t)(n0 + rl) * E_DIM + gsw * 8;

    f32x4 acc[8][4];
    const f32x4 zero = {0.f, 0.f, 0.f, 0.f};
#pragma unroll
    for (int mt = 0; mt < 8; ++mt)
#pragma unroll
        for (int nt = 0; nt < 4; ++nt) acc[mt][nt] = zero;

    // stage panel of step tt: 2 gload_lds per thread per matrix
#define STAGE_A8(tt) do {                                                     \
        const int b_ = (tt) & 3;                                              \
        _Pragma("unroll")                                                     \
        for (int i_ = 0; i_ < 2; ++i_) {                                      \
            const int c_ = i_ * 8 + w;                                        \
            load_lds16(Ag + (size_t)(c_ * 16) * E_DIM + (tt) * 32,            \
                       SA + b_ * 8192 + c_ * 512);                            \
        } } while (0)
#define STAGE_B8(tt) do {                                                     \
        const int b_ = (tt) & 3;                                              \
        _Pragma("unroll")                                                     \
        for (int i_ = 0; i_ < 2; ++i_) {                                      \
            const int c_ = i_ * 8 + w;                                        \
            load_lds16(Bg + (size_t)(c_ * 16) * E_DIM + (tt) * 32,            \
                       SB + b_ * 8192 + c_ * 512);                            \
        } } while (0)

    // prologue: stage steps 0,1,2 (12 loads/thread); wait oldest 4 (step 0)
#pragma unroll
    for (int tt = 0; tt < 3; ++tt) { STAGE_A8(tt); STAGE_B8(tt); }
    asm volatile("s_waitcnt vmcnt(8)" ::: "memory");
    __builtin_amdgcn_s_barrier();
    asm volatile("" ::: "memory");

    for (int t = 0; t < 32; ++t) {
        const ushort* Ab = SA + (t & 3) * 8192;
        const ushort* Bb = SB + (t & 3) * 8192;

        // ---- phase A: bfr[0..3] + af[0..3], stage A(t+3), 16 MFMA ----
        bf16x8 bfr[4], af[4];
#pragma unroll
        for (int nt = 0; nt < 4; ++nt)
            bfr[nt] = *(const bf16x8*)(Bb + (wn * 64 + nt * 16 + l16) * 32 + cpq);
#pragma unroll
        for (int mt = 0; mt < 4; ++mt)
            af[mt] = *(const bf16x8*)(Ab + (wm * 128 + mt * 16 + l16) * 32 + cpq);
        if (t + 3 < 32) STAGE_A8(t + 3);
        __builtin_amdgcn_s_barrier();
        __builtin_amdgcn_sched_barrier(0);
        __builtin_amdgcn_s_setprio(1);
#pragma unroll
        for (int mt = 0; mt < 4; ++mt)
#pragma unroll
            for (int nt = 0; nt < 4; ++nt)
                acc[mt][nt] = __builtin_amdgcn_mfma_f32_16x16x32_bf16(
                    af[mt], bfr[nt], acc[mt][nt], 0, 0, 0);
        __builtin_amdgcn_s_setprio(0);
        __builtin_amdgcn_s_barrier();
        asm volatile("" ::: "memory");

        // ---- phase B: af[4..7], stage B(t+3), 16 MFMA, counted vmcnt ----
        bf16x8 af2[4];
#pragma unroll
        for (int mt = 0; mt < 4; ++mt)
            af2[mt] = *(const bf16x8*)(Ab + (wm * 128 + (4 + mt) * 16 + l16) * 32 + cpq);
        if (t + 3 < 32) STAGE_B8(t + 3);
        __builtin_amdgcn_s_barrier();
        __builtin_amdgcn_sched_barrier(0);
        __builtin_amdgcn_s_setprio(1);
#pragma unroll
        for (int mt = 0; mt < 4; ++mt)
#pragma unroll
            for (int nt = 0; nt < 4; ++nt)
                acc[4 + mt][nt] = __builtin_amdgcn_mfma_f32_16x16x32_bf16(
                    af2[mt], bfr[nt], acc[4 + mt][nt], 0, 0, 0);
        __builtin_amdgcn_s_setprio(0);
        // counted wait: guarantee panels t+1 retired before next step's reads;
        // never 0 until the tail (outstanding = newest 2-4 panels stay in flight)
        if (t <= 28)      asm volatile("s_waitcnt vmcnt(8)" ::: "memory");
        else if (t == 29) asm volatile("s_waitcnt vmcnt(4)" ::: "memory");
        else if (t == 30) asm volatile("s_waitcnt vmcnt(0)" ::: "memory");
        __builtin_amdgcn_s_barrier();
        asm volatile("" ::: "memory");
    }
#undef STAGE_A8
#undef STAGE_B8

    // ---- epilogue (verified in round 2) ------------------------------------
    const int z    = n0 >> 10;           // 0:K 1:Q 2:V (blocks never straddle)
    const int ncol = n0 & 1023;
    const int col0 = ncol + wn * 64;     // 64-aligned -> exactly one head
    const int row0 = m0 + wm * 128;

    if (z < 2) {
        ushort* C = z ? Qb : Kb;
        const float* lw = z ? qw : kw;
        const float* lb = z ? qbias : kbias;
        const float scale = z ? (0.125f * LOG2E) : 1.0f;
        float wv[4], bv_[4];
#pragma unroll
        for (int nt = 0; nt < 4; ++nt) {
            wv[nt]  = lw[nt * 16 + l16];
            bv_[nt] = lb[nt * 16 + l16];
        }
#pragma unroll
        for (int mt = 0; mt < 8; ++mt)
#pragma unroll
            for (int r = 0; r < 4; ++r) {
                float v[4], d[4];
#pragma unroll
                for (int nt = 0; nt < 4; ++nt) v[nt] = acc[mt][nt][r];
                float s = v[0] + v[1] + v[2] + v[3];
                s += __shfl_xor(s, 1); s += __shfl_xor(s, 2);
                s += __shfl_xor(s, 4); s += __shfl_xor(s, 8);
                float mu = s * (1.0f / 64.0f);
                float q2 = 0.f;
#pragma unroll
                for (int nt = 0; nt < 4; ++nt) { d[nt] = v[nt] - mu; q2 += d[nt] * d[nt]; }
                q2 += __shfl_xor(q2, 1); q2 += __shfl_xor(q2, 2);
                q2 += __shfl_xor(q2, 4); q2 += __shfl_xor(q2, 8);
                float rin = rsqrtf(q2 * (1.0f / 64.0f) + 1e-5f);
                int row = row0 + mt * 16 + quad * 4 + r;
#pragma unroll
                for (int nt = 0; nt < 4; ++nt)
                    C[(size_t)row * E_DIM + col0 + nt * 16 + l16] =
                        f2bf((d[nt] * rin * wv[nt] + bv_[nt]) * scale);
            }
    } else {
        // V: transposed store Vt[(b*NH+h)*64 + d][t]
        const int bidx = m0 >> 11;
        const int hh   = col0 >> 6;
        const int t0   = (m0 & 2047) + wm * 128;
#pragma unroll
        for (int mt = 0; mt < 8; ++mt)
#pragma unroll
            for (int nt = 0; nt < 4; ++nt) {
                ushort4 pk = make_ushort4(f2bf(acc[mt][nt][0]), f2bf(acc[mt][nt][1]),
                                          f2bf(acc[mt][nt][2]), f2bf(acc[mt][nt][3]));
                size_t off = ((size_t)(bidx * NH + hh) * 64 + nt * 16 + l16) * T_SEQ
                             + t0 + mt * 16 + quad * 4;
                *(ushort4*)(Vt + off) = pk;
            }
    }
}

// ---------------------------------------------------------------------------
// Output GEMM: 128x128 tiles (grid 8x32 = 256 blocks), dbuf core, fp32 store.
// ---------------------------------------------------------------------------
__global__ __launch_bounds__(256) void gemm_o(
    const ushort* __restrict__ A, const ushort* __restrict__ W,
    float* __restrict__ C)
{
    __shared__ ushort As[2 * 128 * 32];
    __shared__ ushort Bs[2 * 128 * 32];
    const int m0 = blockIdx.y * 128, n0 = blockIdx.x * 128;
    f32x4 acc[4][4];
    gemm_core_db(A, W, m0, n0, As, Bs, acc);

    const int lane = threadIdx.x & 63, w = threadIdx.x >> 6;
    const int quad = lane >> 4, l16 = lane & 15;
    const int row0 = m0 + (w & 1) * 64;
    const int col0 = n0 + (w >> 1) * 64;
#pragma unroll
    for (int mt = 0; mt < 4; ++mt)
#pragma unroll
        for (int nt = 0; nt < 4; ++nt)
#pragma unroll
            for (int r = 0; r < 4; ++r)
                C[(size_t)(row0 + mt * 16 + quad * 4 + r) * E_DIM
                  + col0 + nt * 16 + l16] = acc[mt][nt][r];
}

// ---------------------------------------------------------------------------
// Flash attention v5 (causal, bf16 MFMA, exp2 fixed-max softmax,
// register-direct PV via S^T). Proven 43 µs, balance-swizzled grid.
// ---------------------------------------------------------------------------
__global__ __launch_bounds__(256, 4) void flash_attn5(
    const ushort* __restrict__ Qg, const ushort* __restrict__ Kg,
    const ushort* __restrict__ Vt, ushort* __restrict__ O)
{
    __shared__ ushort Ks[2][64 * 64];   // 16 KB
    __shared__ ushort Vs[2][64 * 64];   // 16 KB

    const int tid  = threadIdx.x;
    const int lane = tid & 63, w = tid >> 6;
    const int quad = lane >> 4, l16 = lane & 15;

    // balance swizzle: class c gets qt in {q0, 15-q0, 16+q0, 31-q0} (sum 66)
    const int L = blockIdx.x;           // 0..1023
    const int c = L & 255, s = L >> 8;
    const int q0 = c >> 5;              // 0..7
    const int bh = c & 31;
    const int qt = (s == 0) ? q0 : (s == 1) ? (15 - q0)
                 : (s == 2) ? (16 + q0) : (31 - q0);
    const int b = bh >> 4, h = bh & 15;

    const ushort* Qbase = Qg + ((size_t)b * T_SEQ) * E_DIM + h * HS;
    const ushort* Kbase = Kg + ((size_t)b * T_SEQ) * E_DIM + h * HS;
    const ushort* Vbase = Vt + ((size_t)bh * HS) * T_SEQ;   // [d][t]

    const int rloc = lane >> 3;
    const int gswc = (lane & 7) ^ rloc;     // swizzled global chunk (staging)
    const int sw   = l16 & 7;               // frag-read xor factor

    // Q B-frags (16x16x32): B[n=q][k=d], lane n=l16 -> q row, k=quad*8+j
    bf16x8 aq[2];
#pragma unroll
    for (int ks = 0; ks < 2; ++ks)
        aq[ks] = *(const bf16x8*)(Qbase + (size_t)(qt * 64 + w * 16 + l16) * E_DIM
                                  + ks * 32 + quad * 8);

    const f32x4 zero = {0.f, 0.f, 0.f, 0.f};
    f32x4 o_acc[4];                     // O^T: lane col=q(l16), rows d=quad*4+r
#pragma unroll
    for (int dt = 0; dt < 4; ++dt) o_acc[dt] = zero;
    float l_acc = 0.f;                  // q is lane-fixed -> scalar l

    // initial stage into buffer 0
#pragma unroll
    for (int i = 0; i < 2; ++i) {
        int cc = w * 2 + i, row = cc * 8 + rloc;
        load_lds16(Kbase + (size_t)row * E_DIM + gswc * 8, Ks[0] + cc * 512);
        load_lds16(Vbase + (size_t)row * T_SEQ + gswc * 8, Vs[0] + cc * 512);
    }

    const float M8 = 8.0f * LOG2E;   // fixed max in exp2 domain

    for (int jt = 0; jt <= qt; ++jt) {
        const int buf = jt & 1;
        __syncthreads();   // drains vmcnt -> buf ready; syncs buffer reuse
        if (jt < qt) {
#pragma unroll
            for (int i = 0; i < 2; ++i) {
                int cc = w * 2 + i, row = cc * 8 + rloc;
                load_lds16(Kbase + (size_t)(jt + 1) * 64 * E_DIM
                           + (size_t)row * E_DIM + gswc * 8, Ks[buf ^ 1] + cc * 512);
                load_lds16(Vbase + (size_t)row * T_SEQ + (jt + 1) * 64 + gswc * 8,
                           Vs[buf ^ 1] + cc * 512);
            }
        }

        // S^T = K Q^T: tiles over t (nt). A=K-frag (m=t), B=aq (n=q).
        f32x4 sa[4];
#pragma unroll
        for (int nt = 0; nt < 4; ++nt) sa[nt] = zero;
#pragma unroll
        for (int ks = 0; ks < 2; ++ks) {
            int cp = ((ks * 4 + quad) ^ sw) * 8;
#pragma unroll
            for (int nt = 0; nt < 4; ++nt) {
                bf16x8 bk = *(const bf16x8*)(Ks[buf] + (nt * 16 + l16) * 64 + cp);
                sa[nt] = __builtin_amdgcn_mfma_f32_16x16x32_bf16(bk, aq[ks], sa[nt], 0, 0, 0);
            }
        }

        if (jt == qt) {   // causal mask: t > q  (tile-local coords, same origin)
#pragma unroll
            for (int nt = 0; nt < 4; ++nt)
#pragma unroll
                for (int r = 0; r < 4; ++r)
                    if (nt * 16 + quad * 4 + r > w * 16 + l16) sa[nt][r] = -1e30f;
        }

        // p = exp2(s - 8*log2e); scalar l accumulation; pack B-frags (trunc)
        bf16x4 bp[4];
#pragma unroll
        for (int nt = 0; nt < 4; ++nt)
#pragma unroll
            for (int r = 0; r < 4; ++r) {
                float p = __builtin_amdgcn_exp2f(sa[nt][r] - M8);
                l_acc += p;
                bp[nt][r] = (short)f2bf_trunc(p);
            }

        // O^T += V^T @ P^T : A = V^T rows d (from Vs), B = bp[kt] (k = t)
#pragma unroll
        for (int kt = 0; kt < 4; ++kt) {
            const int tt = kt * 16 + quad * 4;          // t of this k-slice
            const int ch = tt >> 3, el = tt & 7;
#pragma unroll
            for (int dt = 0; dt < 4; ++dt) {
                const int vd = dt * 16 + l16;
                bf16x4 va = *(const bf16x4*)(Vs[buf] + vd * 64
                                             + ((ch ^ (vd & 7)) << 3) + el);
                o_acc[dt] = mfma16(va, bp[kt], o_acc[dt]);
            }
        }
    }

    // Epilogue: l reduce across quads (q = l16 fixed), divide, pack, store.
    l_acc += __shfl_xor(l_acc, 16);
    l_acc += __shfl_xor(l_acc, 32);
    const float inv = 1.0f / l_acc;
    const int trow = qt * 64 + w * 16 + l16;
#pragma unroll
    for (int dt = 0; dt < 4; ++dt) {
        ushort4 pk = make_ushort4(f2bf(o_acc[dt][0] * inv), f2bf(o_acc[dt][1] * inv),
                                  f2bf(o_acc[dt][2] * inv), f2bf(o_acc[dt][3] * inv));
        *(ushort4*)(O + ((size_t)b * T_SEQ + trow) * E_DIM + h * HS
                    + dt * 16 + quad * 4) = pk;
    }
}

// ---------------------------------------------------------------------------
extern "C" void kernel_launch(void* const* d_in, const int* in_sizes, int n_in,
                              void* d_out, int out_size, void* d_ws, size_t ws_size,
                              hipStream_t stream) {
    const float* x     = (const float*)d_in[0];
    const float* Wk    = (const float*)d_in[1];
    const float* Wq    = (const float*)d_in[2];
    const float* Wv    = (const float*)d_in[3];
    const float* Wu    = (const float*)d_in[4];
    const float* kln_w = (const float*)d_in[5];
    const float* kln_b = (const float*)d_in[6];
    const float* qln_w = (const float*)d_in[7];
    const float* qln_b = (const float*)d_in[8];
    float* out = (float*)d_out;

    const size_t NE = (size_t)M_ROWS * E_DIM;   // 4M elems
    const size_t NW = (size_t)E_DIM * E_DIM;    // 1M elems
    ushort* xb  = (ushort*)d_ws;                // 4M
    ushort* Wkb = xb  + NE;                     // 1M each; Wk;Wq;Wv contiguous
    ushort* Wqb = Wkb + NW;                     //   -> packed Wqkv [3072][1024]
    ushort* Wvb = Wqb + NW;
    ushort* Wub = Wvb + NW;
    ushort* Kb  = Wub + NW;                     // 4M
    ushort* Qb  = Kb  + NE;                     // 4M
    ushort* Vt  = Qb  + NE;                     // 4M, [bh][d][t]
    ushort* Ob  = Vt  + NE;                     // 4M

    // one-time: allow 128 KiB dynamic LDS for the 8-phase core
    static int attr_done = 0;
    if (!attr_done) {
        hipFuncSetAttribute(reinterpret_cast<const void*>(gemm_qkv_8p),
                            hipFuncAttributeMaxDynamicSharedMemorySize, 131072);
        attr_done = 1;
    }

    // 1) fp32 -> bf16 (weights land packed: [Wk;Wq;Wv] = Wqkv)
    cvt_all<<<8192, 256, 0, stream>>>(x, Wk, Wq, Wv, Wu, xb, Wkb, Wqb, Wvb, Wub);

    // 2) Fused QKV projection (256^2, phase-interleaved counted-vmcnt core)
    gemm_qkv_8p<<<192, 512, 131072, stream>>>(
        xb, Wkb, Kb, Qb, Vt, kln_w, kln_b, qln_w, qln_b);

    // 3) Causal flash attention (register-direct PV)
    flash_attn5<<<1024, 256, 0, stream>>>(Qb, Kb, Vt, Ob);

    // 4) Output projection (128x128, dbuf) -> fp32 out
    gemm_o<<<dim3(E_DIM / 128, M_ROWS / 128), 256, 0, stream>>>(Ob, Wub, out);
}